// Round 1
// baseline (26.474 us; speedup 1.0000x reference)
//
#include <hip/hip_runtime.h>
#include <math.h>

// B=256, K=51, N=8192. out = MULT * sum_{b,d} sqrt(w_b^T G_d w_b),
// w = y_hat - y, G_d[k1,k2] = sum_n bs[k1,n,d]*bs[k2,n,d].
// (face cancels; EPS cross-term ~1e-6 relative -> dropped, validated round 1.)
//
// Two dispatches:
//   K1 pl_gram           : 192 blocks, per-(d,chunk) partial Gram via MFMA.
//                          Also zero-inits ctr/out for K2 (kernel-boundary
//                          visibility makes this free and race-free).
//   K2 pl_reduce_finalize: 48 blocks. Each reduces its 256-el slice of G,
//                          publishes via agent release fence + atomic ticket,
//                          spins till all 48 slices land (all blocks increment
//                          BEFORE spinning and 48 <= 256 CUs -> no deadlock),
//                          acquire fence, then finalize (unchanged math).
#define NPTS     8192
#define KDIM     51
#define KPAD     64
#define CHUNKS   64
#define CHUNK_N  128
#define MULT     0.0025f

typedef short short8  __attribute__((ext_vector_type(8)));
typedef float float4v __attribute__((ext_vector_type(4)));
// dword-aligned (NOT 16B) float4 for the staging trick below
typedef float float4a __attribute__((ext_vector_type(4), aligned(4)));

// RNE f32 -> bf16 bits (inputs are normal floats; NaN path irrelevant)
__device__ __forceinline__ unsigned short f32_to_bf16(float f) {
    unsigned int u = __float_as_uint(f);
    unsigned int r = u + 0x7FFFu + ((u >> 16) & 1u);
    return (unsigned short)(r >> 16);
}

// ---------------------------------------------------------------------------
// Kernel 1: per-(d, 128-point chunk) partial Gram via MFMA bf16.
// LDS: lds16[shape][point], stride 136 bf16 (=68 dwords; 68%32=4 -> rows
// rotate banks, staged pair-writes are 2-way = free). Each of 4 waves owns a
// 32x32 quadrant as 2x2 16x16 tiles; K-loop 4 iters of K=32 points.
// mfma_f32_16x16x32_bf16 layouts (HW-verified, guide §3):
//   A: m=lane&15, k=(lane>>4)*8+j  (8 contiguous points)   B: mirror
//   C: col=lane&15, row=(lane>>4)*4+reg
// G symmetric => robust to A/B role mixups; only k-mapping must match (it does).
// ---------------------------------------------------------------------------
__global__ __launch_bounds__(256) void pl_gram(
    const float* __restrict__ bs, float* __restrict__ partial,
    unsigned int* __restrict__ ctr, float* __restrict__ out) {
  __shared__ unsigned short lds16[KPAD * 136];

  const int bx  = blockIdx.x;
  const int d   = bx / CHUNKS;
  const int n0  = (bx % CHUNKS) * CHUNK_N;
  const int tid = threadIdx.x;

  // Init for K2 (K1 completes before K2 starts -> kernel-boundary visibility).
  if (bx == 0 && tid == 0) { out[0] = 0.0f; ctr[0] = 0u; }

  // Stage: u -> (shape k = u>>6, point-pair np = u&63). Lanes: np consecutive,
  // k fixed -> LDS banks (4k+np)%32 = all 32, 2-way (free). Global: one
  // dword-aligned dwordx4 covers both points of the pair (elements 0 and 3:
  // addresses 3n+d and 3(n+1)+d) -> halves staging load instrs vs 2 scalars.
  // Last pair's element 3 is exactly the final bs element: no OOB.
  unsigned int* lds32 = (unsigned int*)lds16;
  for (int u = tid; u < KPAD * (CHUNK_N / 2); u += 256) {
    int np = u & 63;
    int k  = u >> 6;
    float v0 = 0.0f, v1 = 0.0f;
    if (k < KDIM) {
      const float* p = bs + (size_t)k * (NPTS * 3) + (size_t)(n0 + 2 * np) * 3 + d;
      float4a f = *(const float4a*)p;
      v0 = f[0];
      v1 = f[3];
    }
    lds32[k * 68 + np] = (unsigned int)f32_to_bf16(v0) |
                         ((unsigned int)f32_to_bf16(v1) << 16);
  }
  __syncthreads();

  const int wave  = tid >> 6;
  const int lane  = tid & 63;
  const int m16   = lane & 15;
  const int quad  = lane >> 4;
  const int rbase = (wave >> 1) * 32;
  const int cbase = (wave & 1) * 32;

  float4v acc00 = {0.f, 0.f, 0.f, 0.f}, acc01 = {0.f, 0.f, 0.f, 0.f};
  float4v acc10 = {0.f, 0.f, 0.f, 0.f}, acc11 = {0.f, 0.f, 0.f, 0.f};

#pragma unroll
  for (int p0 = 0; p0 < CHUNK_N; p0 += 32) {
    const int po = p0 + quad * 8;
    short8 a0 = *(const short8*)&lds16[(rbase +      m16) * 136 + po];
    short8 a1 = *(const short8*)&lds16[(rbase + 16 + m16) * 136 + po];
    short8 b0 = *(const short8*)&lds16[(cbase +      m16) * 136 + po];
    short8 b1 = *(const short8*)&lds16[(cbase + 16 + m16) * 136 + po];
    acc00 = __builtin_amdgcn_mfma_f32_16x16x32_bf16(a0, b0, acc00, 0, 0, 0);
    acc01 = __builtin_amdgcn_mfma_f32_16x16x32_bf16(a0, b1, acc01, 0, 0, 0);
    acc10 = __builtin_amdgcn_mfma_f32_16x16x32_bf16(a1, b0, acc10, 0, 0, 0);
    acc11 = __builtin_amdgcn_mfma_f32_16x16x32_bf16(a1, b1, acc11, 0, 0, 0);
  }

  // Emit in NATURAL [row][col] layout. Shapes >=51 are zero-padded -> rows/
  // cols >=51 hold exact zeros (valid to reduce).
  float* pout = partial + (size_t)bx * 4096;
#pragma unroll
  for (int r = 0; r < 4; ++r) {
    int row0 = rbase + quad * 4 + r;
    int col0 = cbase + m16;
    pout[row0 * 64 + col0]               = acc00[r];
    pout[row0 * 64 + (col0 + 16)]        = acc01[r];
    pout[(row0 + 16) * 64 + col0]        = acc10[r];
    pout[(row0 + 16) * 64 + (col0 + 16)] = acc11[r];
  }
}

// ---------------------------------------------------------------------------
// Kernel 2: fused reduce + finalize. 48 blocks = 3 d x 16 groups of 16 rows.
// Phase A: block reduces its 256-element slice of G_d (exact same c-loop
//          summation order as the old reduce kernel -> bitwise-identical G).
// Sync   : agent release fence + atomic ticket; spin to 48; acquire fence.
// Phase C: unchanged finalize: q[b,d] = w_b^T G_d w_b; out += MULT*sum(sqrt).
// ---------------------------------------------------------------------------
__global__ __launch_bounds__(256) void pl_reduce_finalize(
    const float* __restrict__ partial, float* __restrict__ G,
    unsigned int* __restrict__ ctr, const float* __restrict__ yh,
    const float* __restrict__ yv, float* __restrict__ out) {
  __shared__ float Gl[64 * 65];   // stride 65: bank-safe rows
  __shared__ float wl[16 * 52];
  __shared__ float red2[16];

  const int bx  = blockIdx.x;     // 48 = 3 d x 16 groups
  const int d   = bx >> 4;
  const int b0  = (bx & 15) << 4;
  const int tid = threadIdx.x;

  // Phase A: 256 threads = 256 consecutive elements of G_d.
  {
    const int e_d = ((bx & 15) << 8) + tid;
    const float* p = partial + (size_t)(d * CHUNKS) * 4096 + e_d;
    float s = 0.0f;
    for (int c = 0; c < CHUNKS; ++c) s += p[(size_t)c * 4096];
    G[d * 4096 + e_d] = s;
  }

  // Stage w while the other 47 slices land (independent of G).
  for (int idx = tid; idx < 16 * KDIM; idx += 256) {
    int bl = idx / KDIM, k = idx - bl * KDIM;
    int gi = (b0 + bl) * KDIM + k;
    wl[bl * 52 + k] = yh[gi] - yv[gi];
  }
  __syncthreads();                // all G-slice stores retired to L2
  if (tid == 0) {
    __threadfence();              // agent release: writeback my slice
    __hip_atomic_fetch_add(ctr, 1u, __ATOMIC_ACQ_REL, __HIP_MEMORY_SCOPE_AGENT);
    while (__hip_atomic_load(ctr, __ATOMIC_ACQUIRE, __HIP_MEMORY_SCOPE_AGENT) < 48u)
      __builtin_amdgcn_s_sleep(2);
  }
  __syncthreads();
  __threadfence();                // agent acquire: invalidate stale lines

  for (int idx = tid; idx < 4096; idx += 256)
    Gl[(idx >> 6) * 65 + (idx & 63)] = G[d * 4096 + idx];
  __syncthreads();

  const int bl = tid >> 4;
  const int j  = tid & 15;
  float pq = 0.0f;
  for (int k1 = j; k1 < KDIM; k1 += 16) {
    float t = 0.0f;
    const float* gr = &Gl[k1 * 65];
    const float* wr = &wl[bl * 52];
#pragma unroll
    for (int k2 = 0; k2 < KDIM; ++k2) t = fmaf(gr[k2], wr[k2], t);
    pq = fmaf(wl[bl * 52 + k1], t, pq);
  }
  for (int off = 8; off; off >>= 1) pq += __shfl_down(pq, off, 16);
  if (j == 0) red2[bl] = sqrtf(pq);
  __syncthreads();
  if (tid == 0) {
    float s = 0.0f;
#pragma unroll
    for (int i = 0; i < 16; ++i) s += red2[i];
    atomicAdd(out, s * MULT);
  }
}

extern "C" void kernel_launch(void* const* d_in, const int* in_sizes, int n_in,
                              void* d_out, int out_size, void* d_ws, size_t ws_size,
                              hipStream_t stream) {
  const float* y_hat = (const float*)d_in[0];   // [256,51]
  const float* y     = (const float*)d_in[1];   // [256,51]
  // d_in[2] = face [8192,3] — cancels algebraically, unused
  const float* bs    = (const float*)d_in[3];   // [51,8192,3]
  float* out = (float*)d_out;

  float* partial    = (float*)d_ws;                          // 192*4096 floats
  float* G          = partial + (size_t)3 * CHUNKS * 4096;   // 3*4096 floats
  unsigned int* ctr = (unsigned int*)(G + 3 * 4096);         // 1 uint

  pl_gram<<<3 * CHUNKS, 256, 0, stream>>>(bs, partial, ctr, out);
  pl_reduce_finalize<<<48, 256, 0, stream>>>(partial, G, ctr, y_hat, y, out);
}

// Round 2
// 19.433 us; speedup vs baseline: 1.3623x; 1.3623x over previous
//
#include <hip/hip_runtime.h>
#include <math.h>

// B=256, K=51, N=8192. out = MULT * sum_{b,d} sqrt(w_b^T G_d w_b),
// w = y_hat - y, G_d[k1,k2] = sum_n bs[k1,n,d]*bs[k2,n,d].
// (face cancels; EPS cross-term ~1e-6 relative -> dropped, validated earlier.)
//
// Two dispatches, NO grid-wide barrier (round-1 lesson: all-block
// release+acquire+spin on 8 non-coherent XCD L2s cost +4 us):
//   K1 pl_gram (193 blocks): blocks 0..191 produce per-(d,chunk) partial
//      Grams via MFMA. Block 192 zero-inits pq[768] + ctr (visible to K2 via
//      the kernel boundary).
//   K2 pl_finalize (156 blocks = 3 d x 13 rowgroups x 4 batchgroups):
//      q[b,d] = sum_k1 w[b,k1]*(G_row_k1 . w_b) is ADDITIVE over rowgroups,
//      so each block: reduce its 4 Gram rows over 64 chunks (same serial
//      order as before), compute partial quadratic forms for its 64 batch
//      rows, atomicAdd into pq (device-scope atomics = LLC, fence-free).
//      Completion: per-block RELEASE fetch_add on ctr (few dirty lines ->
//      cheap; no inv, no spin; blocks exit). The block seeing old==155 does
//      ONE acquire and the 768-element sqrt-sum via agent-scope loads
//      (bypass possibly-stale L2 zeros from K1's init), stores out.
#define NPTS     8192
#define KDIM     51
#define KPAD     64
#define CHUNKS   64
#define CHUNK_N  128
#define MULT     0.0025f

typedef short short8  __attribute__((ext_vector_type(8)));
typedef float float4v __attribute__((ext_vector_type(4)));
// dword-aligned (NOT 16B) float4 for the staging trick below
typedef float float4a __attribute__((ext_vector_type(4), aligned(4)));

// RNE f32 -> bf16 bits (inputs are normal floats; NaN path irrelevant)
__device__ __forceinline__ unsigned short f32_to_bf16(float f) {
    unsigned int u = __float_as_uint(f);
    unsigned int r = u + 0x7FFFu + ((u >> 16) & 1u);
    return (unsigned short)(r >> 16);
}

// ---------------------------------------------------------------------------
// Kernel 1: per-(d, 128-point chunk) partial Gram via MFMA bf16.
// LDS: lds16[shape][point], stride 136 bf16 (=68 dwords; 68%32=4 -> rows
// rotate banks, staged pair-writes are 2-way = free). Each of 4 waves owns a
// 32x32 quadrant as 2x2 16x16 tiles; K-loop 4 iters of K=32 points.
// mfma_f32_16x16x32_bf16 layouts (HW-verified, guide §3):
//   A: m=lane&15, k=(lane>>4)*8+j  (8 contiguous points)   B: mirror
//   C: col=lane&15, row=(lane>>4)*4+reg
// G symmetric => robust to A/B role mixups; only k-mapping must match.
// ---------------------------------------------------------------------------
__global__ __launch_bounds__(256) void pl_gram(
    const float* __restrict__ bs, float* __restrict__ partial,
    float* __restrict__ pq, unsigned int* __restrict__ ctr) {
  __shared__ unsigned short lds16[KPAD * 136];

  const int bx  = blockIdx.x;
  const int tid = threadIdx.x;

  // Dedicated init block: zero pq + ctr for K2. Uniform early return (whole
  // block takes this path -> no barrier divergence).
  if (bx == 192) {
    for (int i = tid; i < 768; i += 256) pq[i] = 0.0f;
    if (tid == 0) ctr[0] = 0u;
    return;
  }

  const int d   = bx / CHUNKS;
  const int n0  = (bx % CHUNKS) * CHUNK_N;

  // Stage: u -> (shape k = u>>6, point-pair np = u&63). Lanes: np consecutive,
  // k fixed -> LDS banks (4k+np)%32 = all 32, 2-way (free). Global: one
  // dword-aligned dwordx4 covers both points of the pair (elements 0 and 3:
  // addresses 3n+d and 3(n+1)+d). Last pair's element 3 is exactly the final
  // bs element: no OOB. d-sibling blocks (bx+-64, same XCD under %8 mapping)
  // reuse the cache lines.
  unsigned int* lds32 = (unsigned int*)lds16;
  for (int u = tid; u < KPAD * (CHUNK_N / 2); u += 256) {
    int np = u & 63;
    int k  = u >> 6;
    float v0 = 0.0f, v1 = 0.0f;
    if (k < KDIM) {
      const float* p = bs + (size_t)k * (NPTS * 3) + (size_t)(n0 + 2 * np) * 3 + d;
      float4a f = *(const float4a*)p;
      v0 = f[0];
      v1 = f[3];
    }
    lds32[k * 68 + np] = (unsigned int)f32_to_bf16(v0) |
                         ((unsigned int)f32_to_bf16(v1) << 16);
  }
  __syncthreads();

  const int wave  = tid >> 6;
  const int lane  = tid & 63;
  const int m16   = lane & 15;
  const int quad  = lane >> 4;
  const int rbase = (wave >> 1) * 32;
  const int cbase = (wave & 1) * 32;

  float4v acc00 = {0.f, 0.f, 0.f, 0.f}, acc01 = {0.f, 0.f, 0.f, 0.f};
  float4v acc10 = {0.f, 0.f, 0.f, 0.f}, acc11 = {0.f, 0.f, 0.f, 0.f};

#pragma unroll
  for (int p0 = 0; p0 < CHUNK_N; p0 += 32) {
    const int po = p0 + quad * 8;
    short8 a0 = *(const short8*)&lds16[(rbase +      m16) * 136 + po];
    short8 a1 = *(const short8*)&lds16[(rbase + 16 + m16) * 136 + po];
    short8 b0 = *(const short8*)&lds16[(cbase +      m16) * 136 + po];
    short8 b1 = *(const short8*)&lds16[(cbase + 16 + m16) * 136 + po];
    acc00 = __builtin_amdgcn_mfma_f32_16x16x32_bf16(a0, b0, acc00, 0, 0, 0);
    acc01 = __builtin_amdgcn_mfma_f32_16x16x32_bf16(a0, b1, acc01, 0, 0, 0);
    acc10 = __builtin_amdgcn_mfma_f32_16x16x32_bf16(a1, b0, acc10, 0, 0, 0);
    acc11 = __builtin_amdgcn_mfma_f32_16x16x32_bf16(a1, b1, acc11, 0, 0, 0);
  }

  // Emit in NATURAL [row][col] layout. Shapes >=51 are zero-padded -> rows/
  // cols >=51 hold exact zeros (valid to reduce; keeps K2's j-loop NaN-free).
  float* pout = partial + (size_t)bx * 4096;
#pragma unroll
  for (int r = 0; r < 4; ++r) {
    int row0 = rbase + quad * 4 + r;
    int col0 = cbase + m16;
    pout[row0 * 64 + col0]               = acc00[r];
    pout[row0 * 64 + (col0 + 16)]        = acc01[r];
    pout[(row0 + 16) * 64 + col0]        = acc10[r];
    pout[(row0 + 16) * 64 + (col0 + 16)] = acc11[r];
  }
}

// ---------------------------------------------------------------------------
// Kernel 2: rowgroup-decomposed reduce+finalize. bx -> (d, rg, bg):
//   d = bx/52, rem = bx%52, rg = rem>>2 (rows rg*4..rg*4+3), bg = rem&3
//   (batch rows bg*64..bg*64+63).
// Phase R: Gl[e] (e = ri*64+col) = sum over 64 chunks, serial c-order.
// Phase W: wl[64][68] = y_hat - y for this batch group; cols 51..63 zeroed
//          (zero-padded G rows/cols then contribute exact 0, never 0*poison).
// Phase C: thread (jt=tid&15, bh=tid>>4); 4 G-row float4s hoisted to regs;
//          per bl (4 batch rows): t[ri] = G_row[ri][strip jt] . w[strip jt],
//          pq_part = sum_ri w[b][rg*4+ri]*t[ri]; shfl-reduce over 16 jt
//          lanes; lane 0 atomicAdd(pq[d*256+b]).
// ---------------------------------------------------------------------------
__global__ __launch_bounds__(256) void pl_finalize(
    const float* __restrict__ partial, float* __restrict__ pq,
    unsigned int* __restrict__ ctr, const float* __restrict__ yh,
    const float* __restrict__ yv, float* __restrict__ out) {
  __shared__ __align__(16) float Gl[256];
  __shared__ __align__(16) float wl[64 * 68];
  __shared__ unsigned int lflag;
  __shared__ float redw[4];

  const int bx  = blockIdx.x;
  const int d   = bx / 52;
  const int rem = bx - d * 52;
  const int rg  = rem >> 2;
  const int b0  = (rem & 3) * 64;
  const int tid = threadIdx.x;

  // Phase R: reduce my 4 Gram rows (256 consecutive floats at rg*256).
  {
    const float* p = partial + (size_t)(d * CHUNKS) * 4096 + rg * 256 + tid;
    float s = 0.0f;
#pragma unroll 16
    for (int c = 0; c < CHUNKS; ++c) s += p[(size_t)c * 4096];
    Gl[tid] = s;
  }

  // Phase W: stage w for my 64 batch rows; zero-pad cols 51..63.
  for (int i = tid; i < 64 * KDIM; i += 256) {
    int bl = i / KDIM, k = i - bl * KDIM;
    int gi = (b0 + bl) * KDIM + k;
    wl[bl * 68 + k] = yh[gi] - yv[gi];
  }
  for (int i = tid; i < 64 * 13; i += 256) {
    int bl = i / 13, c = KDIM + (i - bl * 13);
    wl[bl * 68 + c] = 0.0f;
  }
  __syncthreads();

  // Phase C.
  {
    const int jt = tid & 15;
    const int bh = tid >> 4;
    float4v g4[4];
#pragma unroll
    for (int ri = 0; ri < 4; ++ri)
      g4[ri] = *(const float4v*)&Gl[ri * 64 + jt * 4];

#pragma unroll
    for (int bl = 0; bl < 4; ++bl) {
      const int lb = bl * 16 + bh;
      float4v wj = *(const float4v*)&wl[lb * 68 + jt * 4];
      float4v wk = *(const float4v*)&wl[lb * 68 + rg * 4];
      float pqp = 0.0f;
#pragma unroll
      for (int ri = 0; ri < 4; ++ri) {
        float t = 0.0f;
#pragma unroll
        for (int jj = 0; jj < 4; ++jj) t = fmaf(g4[ri][jj], wj[jj], t);
        pqp = fmaf(wk[ri], t, pqp);
      }
#pragma unroll
      for (int off = 1; off < 16; off <<= 1) pqp += __shfl_xor(pqp, off, 16);
      if (jt == 0) atomicAdd(&pq[d * 256 + b0 + lb], pqp);
    }
  }
  __syncthreads();   // drains each wave's outstanding atomics before release

  if (tid == 0) {
    unsigned int old = __hip_atomic_fetch_add(ctr, 1u, __ATOMIC_RELEASE,
                                              __HIP_MEMORY_SCOPE_AGENT);
    lflag = (old == 155u) ? 1u : 0u;
  }
  __syncthreads();
  if (lflag == 0u) return;   // 155 blocks exit immediately; no spin anywhere

  // Last block: single acquire, then sqrt-sum of all 768 q values.
  if (tid == 0)
    (void)__hip_atomic_load(ctr, __ATOMIC_ACQUIRE, __HIP_MEMORY_SCOPE_AGENT);
  __syncthreads();

  float s = 0.0f;
#pragma unroll
  for (int i = 0; i < 3; ++i) {
    // Agent-scope loads bypass L1/L2 (this XCD's L2 may hold stale zeros
    // from K1's init block); values are final once ctr hit 156.
    float q = __hip_atomic_load(&pq[i * 256 + tid], __ATOMIC_RELAXED,
                                __HIP_MEMORY_SCOPE_AGENT);
    s += sqrtf(q);
  }
  for (int off = 32; off; off >>= 1) s += __shfl_down(s, off, 64);
  if ((tid & 63) == 0) redw[tid >> 6] = s;
  __syncthreads();
  if (tid == 0)
    out[0] = (redw[0] + redw[1] + redw[2] + redw[3]) * MULT;
}

extern "C" void kernel_launch(void* const* d_in, const int* in_sizes, int n_in,
                              void* d_out, int out_size, void* d_ws, size_t ws_size,
                              hipStream_t stream) {
  const float* y_hat = (const float*)d_in[0];   // [256,51]
  const float* y     = (const float*)d_in[1];   // [256,51]
  // d_in[2] = face [8192,3] — cancels algebraically, unused
  const float* bs    = (const float*)d_in[3];   // [51,8192,3]
  float* out = (float*)d_out;

  float* partial    = (float*)d_ws;                          // 192*4096 floats
  float* pq         = partial + (size_t)3 * CHUNKS * 4096;   // 768 floats
  unsigned int* ctr = (unsigned int*)(pq + 768);             // 1 uint

  pl_gram<<<193, 256, 0, stream>>>(bs, partial, pq, ctr);
  pl_finalize<<<156, 256, 0, stream>>>(partial, pq, ctr, y_hat, y, out);
}